// Round 14
// baseline (252.865 us; speedup 1.0000x reference)
//
#include <hip/hip_runtime.h>
#include <hip/hip_bf16.h>
#include <math.h>

#define BQ 32
#define SQ 2048
#define DQ 1024
#define NQ 512
#define MQ (BQ*SQ)
#define BM 128
#define BN 256
#define BK 32

typedef __attribute__((ext_vector_type(8))) short bf16x8;
typedef __attribute__((ext_vector_type(4))) float f32x4;

// compiler-path f32->bf16 (RTNE, pairs into v_cvt_pk_bf16_f32)
__device__ __forceinline__ short f2bf(float f){
  return __builtin_bit_cast(short, __float2bfloat16(f));
}

__device__ __forceinline__ void gload_lds16(const void* g, void* l){
  __builtin_amdgcn_global_load_lds(
      (const __attribute__((address_space(1))) unsigned int*)g,
      (__attribute__((address_space(3))) unsigned int*)l, 16, 0, 0);
}

// ---- prep: transpose gate_w1 [K=1024][N=512] -> bf16 w1t [N=512][K=1024]
__global__ void k_w1t(const float* __restrict__ w1, short* __restrict__ w1t){
  int i = blockIdx.x*256 + threadIdx.x;
  if (i >= NQ*DQ) return;
  int n = i >> 10, k = i & (DQ-1);
  w1t[i] = f2bf(w1[(size_t)k*NQ + n]);
}

// ---- prep: wq[d] = key_w[d,:]·q (d<1024); wq[1024] = key_b·q
__global__ void k_wq(const float* __restrict__ kw, const float* __restrict__ kb,
                     const float* __restrict__ q, float* __restrict__ wq){
  __shared__ float sh[4];
  int d = blockIdx.x, t = threadIdx.x;
  const float* row = (d < DQ) ? (kw + (size_t)d*DQ) : kb;
  float s = 0.f;
  for (int e=t;e<DQ;e+=256) s += row[e]*q[e];
  #pragma unroll
  for (int o=32;o;o>>=1) s += __shfl_down(s,o);
  if ((t&63)==0) sh[t>>6]=s;
  __syncthreads();
  if (t==0) wq[d] = sh[0]+sh[1]+sh[2]+sh[3];
}

// ---- mask dtype detector: 0=int32(0/1), 1=float32(0/1.0f), 2=byte(bool)
__global__ void k_det(const unsigned int* __restrict__ m, int* __restrict__ flag){
  __shared__ int so, sf;
  int t = threadIdx.x;
  if (t==0){ so=0; sf=0; }
  __syncthreads();
  int o=0, f1=0;
  for (int i=t;i<MQ/4;i+=256){
    unsigned v = m[i];
    if (v==0x3F800000u) f1=1;
    else if (v>1u) o=1;
  }
  if (o) atomicOr(&so,1);
  if (f1) atomicOr(&sf,1);
  __syncthreads();
  if (t==0) *flag = so?2:(sf?1:0);
}

// ---- per-batch valid length
__global__ __launch_bounds__(256) void k_len(const void* __restrict__ maskp,
                                             const int* __restrict__ flag,
                                             int* __restrict__ lens){
  __shared__ int sh[4];
  int b = blockIdx.x, t = threadIdx.x;
  int fl = *flag;
  const unsigned char* m8 = (const unsigned char*)maskp;
  const float* mf = (const float*)maskp;
  const int* mi = (const int*)maskp;
  int cnt = 0;
  #pragma unroll
  for (int i=0;i<8;i++){
    size_t idx = (size_t)b*SQ + t + i*256;
    int mm = (fl==2) ? (m8[idx]!=0) : (fl==1) ? (mf[idx]!=0.0f) : (mi[idx]!=0);
    cnt += mm^1;
  }
  #pragma unroll
  for (int o=32;o;o>>=1) cnt += __shfl_down(cnt,o);
  if ((t&63)==0) sh[t>>6]=cnt;
  __syncthreads();
  if (t==0) lens[b] = sh[0]+sh[1]+sh[2]+sh[3];
}

// ---- fused MFMA GEMM: r5/r13 structure + B TRIPLE-buffer + counted-vmcnt
// barriers (no vmcnt(0) drain in the K-loop). 128x256 tile, BK=32,
// 512 thr = 8 waves (2wm x 4wn), wave tile 64x64. XCD-chunked swizzle.
// Ledger: step t issues A(t+1) reg-loads then B(t+2) gloads; at the barrier
// outstanding = B(t+2)x2 -> s_waitcnt vmcnt(2) proves B(t+1) complete.
__global__ __launch_bounds__(512) void k_gate(
    const float* __restrict__ x, const short* __restrict__ w1t,
    const float* __restrict__ wq, const float* __restrict__ w2,
    const float* __restrict__ b1,
    float* __restrict__ gpart, float* __restrict__ xq)
{
  __shared__ __align__(16) short As[2][BM*BK];   // 8KB x2
  __shared__ __align__(16) short Bs[3][BN*BK];   // 16KB x3
  __shared__ float wqs[DQ];                       // 4KB
  __shared__ float red[4][BM];                    // 2KB

  int tid = threadIdx.x;
  int phys = blockIdx.x;
  int bid = ((phys & 7) << 7) | (phys >> 3);     // 1024 blocks, XCD-chunked
  int bm = bid >> 1, bn = bid & 1;
  int m0 = bm*BM;
  int lane = tid & 63, wid = tid >> 6;
  int wm = wid >> 2, wn = wid & 3;
  int lo = lane & 15, hi = lane >> 4;

  wqs[tid]     = wq[tid];
  wqs[tid+512] = wq[tid+512];

  // A staging map: thread t -> row t>>2 (0..127), cols (t&3)*8 .. +8
  int ar = tid >> 2, ac = (tid & 3) * 8;
  const float* asrc = x + (size_t)(m0 + ar)*DQ + ac;
  // B staging: issue i covers tile rows i*128+(t>>2); LDS shorts i*4096 + t*8
  const short* bsrc = w1t + (size_t)(bn*BN + (tid>>2))*DQ + (tid&3)*8;

  float w2v[4], b1v[4];
  #pragma unroll
  for (int fn=0;fn<4;fn++){
    int n = bn*BN + wn*64 + fn*16 + lo;
    w2v[fn] = w2[n]; b1v[fn] = b1[n];
  }

  // ---- prologue: A(0) regs first, then B(0),B(1) gloads
  f32x4 r0 = *(const f32x4*)(asrc);
  f32x4 r1 = *(const f32x4*)(asrc + 4);
  gload_lds16(bsrc,                       &Bs[0][tid*8]);
  gload_lds16(bsrc + (size_t)128*DQ,      &Bs[0][tid*8 + 4096]);
  gload_lds16(bsrc + BK,                  &Bs[1][tid*8]);
  gload_lds16(bsrc + (size_t)128*DQ + BK, &Bs[1][tid*8 + 4096]);
  // wqs visibility (LDS-only sync; vmcnt untouched -> B loads stay in flight)
  asm volatile("s_waitcnt lgkmcnt(0)" ::: "memory");
  __builtin_amdgcn_s_barrier();
  float xqacc = 0.f;
  {
    if (bn == 0){
      f32x4 w0 = *(const f32x4*)(wqs + ac);
      f32x4 w1v = *(const f32x4*)(wqs + ac + 4);
      #pragma unroll
      for (int j=0;j<4;j++)
        xqacc += r0[j]*w0[j] + r1[j]*w1v[j];
    }
    bf16x8 s0;
    #pragma unroll
    for (int j=0;j<4;j++){ s0[j]=f2bf(r0[j]); s0[4+j]=f2bf(r1[j]); }
    *(bf16x8*)(&As[0][ar*BK + ac]) = s0;
  }
  // B(0) proven done (oldest 2 of 4 outstanding); As[0] via lgkmcnt(0)
  asm volatile("s_waitcnt vmcnt(2) lgkmcnt(0)" ::: "memory");
  __builtin_amdgcn_s_barrier();

  f32x4 acc[4][4];
  #pragma unroll
  for (int a=0;a<4;a++)
    #pragma unroll
    for (int b=0;b<4;b++) acc[a][b] = (f32x4){0.f,0.f,0.f,0.f};

  for (int t=0;t<32;t++){
    int cur = t & 1, nxt = cur ^ 1;
    int bcur = t % 3, bnxt = (t+2) % 3;
    int k0n = (t+1)*BK;
    // A(t+1) reg-loads FIRST (oldest -> auto-wait at convert leaves B in flight)
    if (t < 31){
      r0 = *(const f32x4*)(asrc + k0n);
      r1 = *(const f32x4*)(asrc + k0n + 4);
    }
    // B(t+2) gloads
    if (t < 30){
      const short* bk = bsrc + (t+2)*BK;
      gload_lds16(bk,                  &Bs[bnxt][tid*8]);
      gload_lds16(bk + (size_t)128*DQ, &Bs[bnxt][tid*8 + 4096]);
    }
    bf16x8 af[4], bfr[4];
    #pragma unroll
    for (int fm=0;fm<4;fm++)
      af[fm] = *(const bf16x8*)(&As[cur][(wm*64+fm*16+lo)*BK + hi*8]);
    #pragma unroll
    for (int fn=0;fn<4;fn++)
      bfr[fn] = *(const bf16x8*)(&Bs[bcur][(wn*64+fn*16+lo)*BK + hi*8]);
    #pragma unroll
    for (int fm=0;fm<4;fm++)
      #pragma unroll
      for (int fn=0;fn<4;fn++)
        acc[fm][fn] = __builtin_amdgcn_mfma_f32_16x16x32_bf16(af[fm], bfr[fn], acc[fm][fn], 0,0,0);
    if (t < 31){
      if (bn == 0){
        f32x4 w0 = *(const f32x4*)(wqs + k0n + ac);
        f32x4 w1v = *(const f32x4*)(wqs + k0n + ac + 4);
        #pragma unroll
        for (int j=0;j<4;j++)
          xqacc += r0[j]*w0[j] + r1[j]*w1v[j];
      }
      bf16x8 s0;
      #pragma unroll
      for (int j=0;j<4;j++){ s0[j]=f2bf(r0[j]); s0[4+j]=f2bf(r1[j]); }
      *(bf16x8*)(&As[nxt][ar*BK + ac]) = s0;
    }
    // counted barrier: B(t+1) proven done; As[nxt] ds_writes drained; no vmcnt(0)
    asm volatile("s_waitcnt vmcnt(2) lgkmcnt(0)" ::: "memory");
    __builtin_amdgcn_s_barrier();
  }

  // xq: combine the 4 threads per row
  if (bn == 0){
    float s = xqacc;
    s += __shfl_xor(s, 1);
    s += __shfl_xor(s, 2);
    if ((tid & 3) == 0) xq[m0 + ar] = s;
  }

  // epilogue: GELU + dot w2 over this wave's 64 cols -> per-row partial strip
  #pragma unroll
  for (int fm=0;fm<4;fm++){
    #pragma unroll
    for (int j=0;j<4;j++){
      float s = 0.f;
      #pragma unroll
      for (int fn=0;fn<4;fn++){
        float h = acc[fm][fn][j] + b1v[fn];
        float g = 0.5f*h*(1.0f + erff(h*0.70710678118f));
        s += g*w2v[fn];
      }
      s += __shfl_xor(s,1); s += __shfl_xor(s,2);
      s += __shfl_xor(s,4); s += __shfl_xor(s,8);
      if (lo == 0){
        int p = bn*4 + wn;
        gpart[(size_t)p*MQ + m0 + wm*64 + fm*16 + hi*4 + j] = s;
      }
    }
  }
}

// ---- fused w-phase + pooling: 256 blocks x 256 rows.
__global__ __launch_bounds__(256) void k_wpool(
    const float* __restrict__ x, const float* __restrict__ gpart,
    const float* __restrict__ xqv, const float* __restrict__ wq,
    const float* __restrict__ b2p, const float* __restrict__ lamp,
    const void* __restrict__ maskp, const int* __restrict__ flag,
    const int* __restrict__ lens,
    float* __restrict__ part, float* __restrict__ wsumv)
{
  __shared__ float wrow[256];
  __shared__ float ssum[4];
  int blk = blockIdx.x, t = threadIdx.x;
  int batch = blk >> 3;
  int sBase = (blk & 7) * 256;
  size_t R0 = (size_t)blk * 256;
  {
    size_t r = R0 + t;
    float gsum = b2p[0];
    #pragma unroll
    for (int p=0;p<8;p++) gsum += gpart[(size_t)p*MQ + r];
    float gate = 1.0f/(1.0f+expf(-gsum));
    float qb = wq[DQ];
    float lg = (gate*xqv[r] + qb)*0.03125f;
    float lam = lamp[0];
    float posl = fmaxf(lam,0.f) + log1pf(expf(-fabsf(lam)));
    int L = lens[batch];
    int s = sBase + t;
    float pen = fmaxf((float)L - 1.0f - (float)s, 0.0f);
    int fl = *flag;
    size_t mi_ = (size_t)batch*SQ + s;
    int mm = (fl==2) ? (((const unsigned char*)maskp)[mi_]!=0)
           : (fl==1) ? (((const float*)maskp)[mi_]!=0.0f)
                     : (((const int*)maskp)[mi_]!=0);
    float e = mm ? 0.0f : expf(lg - posl*pen);   // softmax denominator term
    wrow[t] = e*gate;                             // pooling weight
    float ts = e;
    #pragma unroll
    for (int o=1;o<64;o<<=1) ts += __shfl_xor(ts,o);
    if ((t&63)==0) ssum[t>>6] = ts;
  }
  __syncthreads();
  if (t==0) wsumv[blk] = ssum[0]+ssum[1]+ssum[2]+ssum[3];

  int d0 = t*4;
  const float* xb = x + R0*DQ + d0;
  f32x4 a = {0.f,0.f,0.f,0.f};
  #pragma unroll 8
  for (int s=0;s<256;s++){
    float w = wrow[s];
    f32x4 v = *(const f32x4*)(xb + (size_t)s*DQ);
    a[0] += w*v[0]; a[1] += w*v[1]; a[2] += w*v[2]; a[3] += w*v[3];
  }
  *(f32x4*)(part + (size_t)blk*DQ + d0) = a;
}

// ---- final: out[b][d] = sum_c part[b*8+c][d] / sum_c wsum[b*8+c]
__global__ __launch_bounds__(256) void k_fin(const float* __restrict__ part,
                                             const float* __restrict__ wsumv,
                                             float* __restrict__ out){
  int i = blockIdx.x*256 + threadIdx.x;   // 32768
  int b = i >> 10, d = i & 1023;
  float den = 0.f;
  #pragma unroll
  for (int c=0;c<8;c++) den += wsumv[b*8+c];
  float s = 0.f;
  #pragma unroll
  for (int c=0;c<8;c++) s += part[((size_t)(b*8+c))*DQ + d];
  out[i] = s/den;
}

extern "C" void kernel_launch(void* const* d_in, const int* in_sizes, int n_in,
                              void* d_out, int out_size, void* d_ws, size_t ws_size,
                              hipStream_t stream)
{
  const float* x    = (const float*)d_in[0];
  const void*  mask = d_in[1];
  const float* w1   = (const float*)d_in[2];
  const float* b1   = (const float*)d_in[3];
  const float* w2   = (const float*)d_in[4];
  const float* b2   = (const float*)d_in[5];
  const float* lam  = (const float*)d_in[6];
  const float* q    = (const float*)d_in[7];
  const float* kw   = (const float*)d_in[8];
  const float* kb   = (const float*)d_in[9];
  char* ws = (char*)d_ws;
  short* w1t   = (short*)ws;                             // 1 MB
  float* wq    = (float*)(ws + (1<<20));                 // 8 KB (1025 floats)
  int*   flag  = (int*)(ws + (1<<20) + 8192);            // 4 B
  int*   lens  = (int*)(ws + (1<<20) + 8448);            // 128 B
  float* wsumv = (float*)(ws + (1<<20) + 12544);         // 1 KB (256)
  float* xqv   = (float*)(ws + (1<<20) + 32768);         // 256 KB
  float* gpart = (float*)(ws + (2<<20));                 // 2 MB (8 x MQ)
  float* part  = (float*)(ws + (4<<20));                 // 1 MB (256 x 1024)
  float* out   = (float*)d_out;

  k_w1t<<<dim3((NQ*DQ+255)/256), 256, 0, stream>>>(w1, w1t);
  k_wq<<<dim3(DQ+1), 256, 0, stream>>>(kw, kb, q, wq);
  k_det<<<dim3(1), 256, 0, stream>>>((const unsigned int*)mask, flag);
  k_len<<<dim3(BQ), 256, 0, stream>>>(mask, flag, lens);
  k_gate<<<dim3((MQ/BM)*(NQ/BN)), 512, 0, stream>>>(x, w1t, wq, w2, b1,
                                                    gpart, xqv);
  k_wpool<<<dim3(MQ/256), 256, 0, stream>>>(x, gpart, xqv, wq, b2, lam,
                                            mask, flag, lens, part, wsumv);
  k_fin<<<dim3((BQ*DQ)/256), 256, 0, stream>>>(part, wsumv, out);
}

// Round 15
// 186.562 us; speedup vs baseline: 1.3554x; 1.3554x over previous
//
#include <hip/hip_runtime.h>
#include <hip/hip_bf16.h>
#include <math.h>

#define BQ 32
#define SQ 2048
#define DQ 1024
#define NQ 512
#define MQ (BQ*SQ)
#define BM 128
#define BN 256
#define BK 32

typedef __attribute__((ext_vector_type(8))) short bf16x8;
typedef __attribute__((ext_vector_type(4))) float f32x4;

// compiler-path f32->bf16 (RTNE, pairs into v_cvt_pk_bf16_f32)
__device__ __forceinline__ short f2bf(float f){
  return __builtin_bit_cast(short, __float2bfloat16(f));
}

__device__ __forceinline__ void gload_lds16(const void* g, void* l){
  __builtin_amdgcn_global_load_lds(
      (const __attribute__((address_space(1))) unsigned int*)g,
      (__attribute__((address_space(3))) unsigned int*)l, 16, 0, 0);
}

// ---- mask dtype detector: 0=int32(0/1), 1=float32(0/1.0f), 2=byte(bool)
__global__ void k_det(const unsigned int* __restrict__ m, int* __restrict__ flag){
  __shared__ int so, sf;
  int t = threadIdx.x;
  if (t==0){ so=0; sf=0; }
  __syncthreads();
  int o=0, f1=0;
  for (int i=t;i<MQ/4;i+=256){
    unsigned v = m[i];
    if (v==0x3F800000u) f1=1;
    else if (v>1u) o=1;
  }
  if (o) atomicOr(&so,1);
  if (f1) atomicOr(&sf,1);
  __syncthreads();
  if (t==0) *flag = so?2:(sf?1:0);
}

// ---- merged prep: blocks [0,2048) w1 transpose; [2048,3073) wq; [3073,3105) len
__global__ __launch_bounds__(256) void k_prep(
    const float* __restrict__ w1, short* __restrict__ w1t,
    const float* __restrict__ kw, const float* __restrict__ kb,
    const float* __restrict__ q, float* __restrict__ wq,
    const void* __restrict__ maskp, const int* __restrict__ flag,
    int* __restrict__ lens)
{
  __shared__ float sh[4];
  int blk = blockIdx.x, t = threadIdx.x;
  if (blk < 2048){
    int i = blk*256 + t;
    int n = i >> 10, k = i & (DQ-1);
    w1t[i] = f2bf(w1[(size_t)k*NQ + n]);
  } else if (blk < 3073){
    int d = blk - 2048;
    const float* row = (d < DQ) ? (kw + (size_t)d*DQ) : kb;
    float s = 0.f;
    for (int e=t;e<DQ;e+=256) s += row[e]*q[e];
    #pragma unroll
    for (int o=32;o;o>>=1) s += __shfl_down(s,o);
    if ((t&63)==0) sh[t>>6]=s;
    __syncthreads();
    if (t==0) wq[d] = sh[0]+sh[1]+sh[2]+sh[3];
  } else {
    int b = blk - 3073;
    int fl = *flag;
    const unsigned char* m8 = (const unsigned char*)maskp;
    const float* mf = (const float*)maskp;
    const int* mi = (const int*)maskp;
    int cnt = 0;
    #pragma unroll
    for (int i=0;i<8;i++){
      size_t idx = (size_t)b*SQ + t + i*256;
      int mm = (fl==2) ? (m8[idx]!=0) : (fl==1) ? (mf[idx]!=0.0f) : (mi[idx]!=0);
      cnt += mm^1;
    }
    #pragma unroll
    for (int o=32;o;o>>=1) cnt += __shfl_down(cnt,o);
    if ((t&63)==0) sh[t>>6]=(float)cnt;
    __syncthreads();
    if (t==0) lens[b] = (int)(sh[0]+sh[1]+sh[2]+sh[3]);
  }
}

// ---- fused MFMA GEMM (r13 champion, byte-exact): h=x@W1 bf16, LDS dbuf,
// epilogue GELU·w2 partials -> gpart[8][MQ]; xq fused in A staging (bn==0).
// 128x256 tile, BK=32, 512 threads = 8 waves (2 wm x 4 wn), wave tile 64x64.
__global__ __launch_bounds__(512) void k_gate(
    const float* __restrict__ x, const short* __restrict__ w1t,
    const float* __restrict__ wq, const float* __restrict__ w2,
    const float* __restrict__ b1,
    float* __restrict__ gpart, float* __restrict__ xq)
{
  __shared__ __align__(16) short As[2][BM*BK];   // 8KB x2
  __shared__ __align__(16) short Bs[2][BN*BK];   // 16KB x2
  __shared__ float wqs[DQ];                       // 4KB

  int tid = threadIdx.x;
  int phys = blockIdx.x;
  int bid = ((phys & 7) << 7) | (phys >> 3);
  int bm = bid >> 1, bn = bid & 1;
  int m0 = bm*BM;
  int lane = tid & 63, wid = tid >> 6;
  int wm = wid >> 2, wn = wid & 3;
  int lo = lane & 15, hi = lane >> 4;

  wqs[tid]     = wq[tid];
  wqs[tid+512] = wq[tid+512];

  int ar = tid >> 2, ac = (tid & 3) * 8;
  const float* asrc = x + (size_t)(m0 + ar)*DQ + ac;
  const short* bsrc = w1t + (size_t)(bn*BN + (tid>>2))*DQ + (tid&3)*8;

  float w2v[4], b1v[4];
  #pragma unroll
  for (int fn=0;fn<4;fn++){
    int n = bn*BN + wn*64 + fn*16 + lo;
    w2v[fn] = w2[n]; b1v[fn] = b1[n];
  }

  // ---- prologue: stage k0=0
  f32x4 r0 = *(const f32x4*)(asrc);
  f32x4 r1 = *(const f32x4*)(asrc + 4);
  gload_lds16(bsrc,                    &Bs[0][tid*8]);
  gload_lds16(bsrc + (size_t)128*DQ,   &Bs[0][tid*8 + 4096]);
  __syncthreads();   // wqs visible; Bs[0] drained (barrier implies vmcnt(0))
  float xqacc = 0.f;
  {
    if (bn == 0){
      f32x4 w0 = *(const f32x4*)(wqs + ac);
      f32x4 w1v = *(const f32x4*)(wqs + ac + 4);
      #pragma unroll
      for (int j=0;j<4;j++)
        xqacc += r0[j]*w0[j] + r1[j]*w1v[j];
    }
    bf16x8 s0;
    #pragma unroll
    for (int j=0;j<4;j++){ s0[j]=f2bf(r0[j]); s0[4+j]=f2bf(r1[j]); }
    *(bf16x8*)(&As[0][ar*BK + ac]) = s0;
  }
  __syncthreads();

  f32x4 acc[4][4];
  #pragma unroll
  for (int a=0;a<4;a++)
    #pragma unroll
    for (int b=0;b<4;b++) acc[a][b] = (f32x4){0.f,0.f,0.f,0.f};

  for (int t=0;t<32;t++){
    int cur = t & 1, nxt = cur ^ 1;
    int k0n = (t+1)*BK;
    if (t < 31){
      r0 = *(const f32x4*)(asrc + k0n);
      r1 = *(const f32x4*)(asrc + k0n + 4);
      gload_lds16(bsrc + k0n,                  &Bs[nxt][tid*8]);
      gload_lds16(bsrc + (size_t)128*DQ + k0n, &Bs[nxt][tid*8 + 4096]);
    }
    bf16x8 af[4], bfr[4];
    #pragma unroll
    for (int fm=0;fm<4;fm++)
      af[fm] = *(const bf16x8*)(&As[cur][(wm*64+fm*16+lo)*BK + hi*8]);
    #pragma unroll
    for (int fn=0;fn<4;fn++)
      bfr[fn] = *(const bf16x8*)(&Bs[cur][(wn*64+fn*16+lo)*BK + hi*8]);
    #pragma unroll
    for (int fm=0;fm<4;fm++)
      #pragma unroll
      for (int fn=0;fn<4;fn++)
        acc[fm][fn] = __builtin_amdgcn_mfma_f32_16x16x32_bf16(af[fm], bfr[fn], acc[fm][fn], 0,0,0);
    if (t < 31){
      if (bn == 0){
        f32x4 w0 = *(const f32x4*)(wqs + k0n + ac);
        f32x4 w1v = *(const f32x4*)(wqs + k0n + ac + 4);
        #pragma unroll
        for (int j=0;j<4;j++)
          xqacc += r0[j]*w0[j] + r1[j]*w1v[j];
      }
      bf16x8 s0;
      #pragma unroll
      for (int j=0;j<4;j++){ s0[j]=f2bf(r0[j]); s0[4+j]=f2bf(r1[j]); }
      *(bf16x8*)(&As[nxt][ar*BK + ac]) = s0;
    }
    __syncthreads();
  }

  // xq: combine the 4 threads per row
  if (bn == 0){
    float s = xqacc;
    s += __shfl_xor(s, 1);
    s += __shfl_xor(s, 2);
    if ((tid & 3) == 0) xq[m0 + ar] = s;
  }

  // epilogue: GELU + dot w2 over this wave's 64 cols -> per-row partial strip
  #pragma unroll
  for (int fm=0;fm<4;fm++){
    #pragma unroll
    for (int j=0;j<4;j++){
      float s = 0.f;
      #pragma unroll
      for (int fn=0;fn<4;fn++){
        float h = acc[fm][fn][j] + b1v[fn];
        float g = 0.5f*h*(1.0f + erff(h*0.70710678118f));
        s += g*w2v[fn];
      }
      s += __shfl_xor(s,1); s += __shfl_xor(s,2);
      s += __shfl_xor(s,4); s += __shfl_xor(s,8);
      if (lo == 0){
        int p = bn*4 + wn;
        gpart[(size_t)p*MQ + m0 + wm*64 + fm*16 + hi*4 + j] = s;
      }
    }
  }
}

// ---- fused w-phase + pooling: 1024 blocks x 64 rows (16 waves/CU occupancy).
__global__ __launch_bounds__(256) void k_wpool(
    const float* __restrict__ x, const float* __restrict__ gpart,
    const float* __restrict__ xqv, const float* __restrict__ wq,
    const float* __restrict__ b2p, const float* __restrict__ lamp,
    const void* __restrict__ maskp, const int* __restrict__ flag,
    const int* __restrict__ lens,
    float* __restrict__ part, float* __restrict__ wsumv)
{
  __shared__ float wrow[64];
  int blk = blockIdx.x, t = threadIdx.x;
  int batch = blk >> 5;            // 32 chunks of 64 rows per batch
  int sBase = (blk & 31) * 64;
  size_t R0 = (size_t)blk * 64;
  if (t < 64){
    size_t r = R0 + t;
    float gsum = b2p[0];
    #pragma unroll
    for (int p=0;p<8;p++) gsum += gpart[(size_t)p*MQ + r];
    float gate = 1.0f/(1.0f+expf(-gsum));
    float qb = wq[DQ];
    float lg = (gate*xqv[r] + qb)*0.03125f;
    float lam = lamp[0];
    float posl = fmaxf(lam,0.f) + log1pf(expf(-fabsf(lam)));
    int L = lens[batch];
    int s = sBase + t;
    float pen = fmaxf((float)L - 1.0f - (float)s, 0.0f);
    int fl = *flag;
    size_t mi_ = (size_t)batch*SQ + s;
    int mm = (fl==2) ? (((const unsigned char*)maskp)[mi_]!=0)
           : (fl==1) ? (((const float*)maskp)[mi_]!=0.0f)
                     : (((const int*)maskp)[mi_]!=0);
    float e = mm ? 0.0f : expf(lg - posl*pen);   // softmax denominator term
    wrow[t] = e*gate;                             // pooling weight
    float ts = e;
    #pragma unroll
    for (int o=1;o<64;o<<=1) ts += __shfl_xor(ts,o);
    if (t==0) wsumv[blk] = ts;
  }
  __syncthreads();

  int d0 = t*4;
  const float* xb = x + R0*DQ + d0;
  f32x4 a = {0.f,0.f,0.f,0.f};
  #pragma unroll 8
  for (int s=0;s<64;s++){
    float w = wrow[s];
    f32x4 v = *(const f32x4*)(xb + (size_t)s*DQ);
    a[0] += w*v[0]; a[1] += w*v[1]; a[2] += w*v[2]; a[3] += w*v[3];
  }
  *(f32x4*)(part + (size_t)blk*DQ + d0) = a;
}

// ---- final: out[b][d] = sum_c part[b*32+c][d] / sum_c wsum[b*32+c]
__global__ __launch_bounds__(256) void k_fin(const float* __restrict__ part,
                                             const float* __restrict__ wsumv,
                                             float* __restrict__ out){
  int i = blockIdx.x*256 + threadIdx.x;   // 32768
  int b = i >> 10, d = i & 1023;
  float den = 0.f;
  #pragma unroll
  for (int c=0;c<32;c++) den += wsumv[b*32+c];
  float s = 0.f;
  #pragma unroll
  for (int c=0;c<32;c++) s += part[((size_t)(b*32+c))*DQ + d];
  out[i] = s/den;
}

extern "C" void kernel_launch(void* const* d_in, const int* in_sizes, int n_in,
                              void* d_out, int out_size, void* d_ws, size_t ws_size,
                              hipStream_t stream)
{
  const float* x    = (const float*)d_in[0];
  const void*  mask = d_in[1];
  const float* w1   = (const float*)d_in[2];
  const float* b1   = (const float*)d_in[3];
  const float* w2   = (const float*)d_in[4];
  const float* b2   = (const float*)d_in[5];
  const float* lam  = (const float*)d_in[6];
  const float* q    = (const float*)d_in[7];
  const float* kw   = (const float*)d_in[8];
  const float* kb   = (const float*)d_in[9];
  char* ws = (char*)d_ws;
  short* w1t   = (short*)ws;                             // 1 MB
  float* wq    = (float*)(ws + (1<<20));                 // 8 KB (1025 floats)
  int*   flag  = (int*)(ws + (1<<20) + 8192);            // 4 B
  int*   lens  = (int*)(ws + (1<<20) + 8448);            // 128 B
  float* wsumv = (float*)(ws + (1<<20) + 12544);         // 4 KB (1024)
  float* xqv   = (float*)(ws + (1<<20) + 32768);         // 256 KB
  float* gpart = (float*)(ws + (2<<20));                 // 2 MB (8 x MQ)
  float* part  = (float*)(ws + (4<<20));                 // 4 MB (1024 x 1024)
  float* out   = (float*)d_out;

  k_det<<<dim3(1), 256, 0, stream>>>((const unsigned int*)mask, flag);
  k_prep<<<dim3(3105), 256, 0, stream>>>(w1, w1t, kw, kb, q, wq,
                                         mask, flag, lens);
  k_gate<<<dim3((MQ/BM)*(NQ/BN)), 512, 0, stream>>>(x, w1t, wq, w2, b1,
                                                    gpart, xqv);
  k_wpool<<<dim3(MQ/64), 256, 0, stream>>>(x, gpart, xqv, wq, b2, lam,
                                           mask, flag, lens, part, wsumv);
  k_fin<<<dim3((BQ*DQ)/256), 256, 0, stream>>>(part, wsumv, out);
}

// Round 16
// 170.284 us; speedup vs baseline: 1.4850x; 1.0956x over previous
//
#include <hip/hip_runtime.h>
#include <hip/hip_bf16.h>
#include <math.h>

#define BQ 32
#define SQ 2048
#define DQ 1024
#define NQ 512
#define MQ (BQ*SQ)
#define BM 128
#define BN 256
#define BK 32

typedef __attribute__((ext_vector_type(8))) short bf16x8;
typedef __attribute__((ext_vector_type(4))) float f32x4;

// compiler-path f32->bf16 (RTNE, pairs into v_cvt_pk_bf16_f32)
__device__ __forceinline__ short f2bf(float f){
  return __builtin_bit_cast(short, __float2bfloat16(f));
}

__device__ __forceinline__ void gload_lds16(const void* g, void* l){
  __builtin_amdgcn_global_load_lds(
      (const __attribute__((address_space(1))) unsigned int*)g,
      (__attribute__((address_space(3))) unsigned int*)l, 16, 0, 0);
}

// ---- mask dtype detector: 0=int32(0/1), 1=float32(0/1.0f), 2=byte(bool)
// Scans 64KB (safe for all dtypes) as uint4.
__global__ void k_det(const uint4* __restrict__ m, int* __restrict__ flag){
  __shared__ int so, sf;
  int t = threadIdx.x;
  if (t==0){ so=0; sf=0; }
  __syncthreads();
  int o=0, f1=0;
  #pragma unroll 4
  for (int i=t;i<MQ/16;i+=256){
    uint4 v = m[i];
    if (v.x==0x3F800000u||v.y==0x3F800000u||v.z==0x3F800000u||v.w==0x3F800000u) f1=1;
    else if (v.x>1u||v.y>1u||v.z>1u||v.w>1u) o=1;
  }
  if (o) atomicOr(&so,1);
  if (f1) atomicOr(&sf,1);
  __syncthreads();
  if (t==0) *flag = so?2:(sf?1:0);
}

// ---- merged prep:
// blocks [0,128): w1 [1024][512] -> bf16 w1t [512][1024], LDS-tiled transpose
// blocks [128,1153): wq[d] = key_w[d,:]·q (d<1024); wq[1024] = key_b·q
// blocks [1153,1185): per-batch valid length (reads flag)
__global__ __launch_bounds__(256) void k_prep(
    const float* __restrict__ w1, short* __restrict__ w1t,
    const float* __restrict__ kw, const float* __restrict__ kb,
    const float* __restrict__ q, float* __restrict__ wq,
    const void* __restrict__ maskp, const int* __restrict__ flag,
    int* __restrict__ lens)
{
  __shared__ float tile[64][65];
  int blk = blockIdx.x, t = threadIdx.x;
  if (blk < 128){
    int kt = blk >> 3, nt = blk & 7;    // 16 k-tiles x 8 n-tiles of 64x64
    int c = t & 63, rq = t >> 6;
    #pragma unroll
    for (int i=0;i<16;i++){
      int r = rq + i*4;                 // coalesced rows
      tile[r][c] = w1[(size_t)(kt*64 + r)*NQ + nt*64 + c];
    }
    __syncthreads();
    #pragma unroll
    for (int i=0;i<16;i++){
      int nr = rq + i*4;
      w1t[(size_t)(nt*64 + nr)*DQ + kt*64 + c] = f2bf(tile[c][nr]);
    }
  } else if (blk < 1153){
    int d = blk - 128;
    const float* row = (d < DQ) ? (kw + (size_t)d*DQ) : kb;
    float s = 0.f;
    for (int e=t;e<DQ;e+=256) s += row[e]*q[e];
    #pragma unroll
    for (int o=32;o;o>>=1) s += __shfl_down(s,o);
    if ((t&63)==0) tile[0][t>>6]=s;
    __syncthreads();
    if (t==0) wq[d] = tile[0][0]+tile[0][1]+tile[0][2]+tile[0][3];
  } else {
    int b = blk - 1153;
    int fl = *flag;
    const unsigned char* m8 = (const unsigned char*)maskp;
    const float* mf = (const float*)maskp;
    const int* mi = (const int*)maskp;
    int cnt = 0;
    #pragma unroll
    for (int i=0;i<8;i++){
      size_t idx = (size_t)b*SQ + t + i*256;
      int mm = (fl==2) ? (m8[idx]!=0) : (fl==1) ? (mf[idx]!=0.0f) : (mi[idx]!=0);
      cnt += mm^1;
    }
    #pragma unroll
    for (int o=32;o;o>>=1) cnt += __shfl_down(cnt,o);
    if ((t&63)==0) tile[0][t>>6]=(float)cnt;
    __syncthreads();
    if (t==0) lens[b] = (int)(tile[0][0]+tile[0][1]+tile[0][2]+tile[0][3]);
  }
}

// ---- fused MFMA GEMM (champion, byte-exact r13/r15): h=x@W1 bf16, LDS dbuf,
// epilogue GELU·w2 partials -> gpart[8][MQ]; xq fused in A staging (bn==0).
// 128x256 tile, BK=32, 512 threads = 8 waves (2 wm x 4 wn), wave tile 64x64.
__global__ __launch_bounds__(512) void k_gate(
    const float* __restrict__ x, const short* __restrict__ w1t,
    const float* __restrict__ wq, const float* __restrict__ w2,
    const float* __restrict__ b1,
    float* __restrict__ gpart, float* __restrict__ xq)
{
  __shared__ __align__(16) short As[2][BM*BK];   // 8KB x2
  __shared__ __align__(16) short Bs[2][BN*BK];   // 16KB x2
  __shared__ float wqs[DQ];                       // 4KB

  int tid = threadIdx.x;
  int phys = blockIdx.x;
  int bid = ((phys & 7) << 7) | (phys >> 3);
  int bm = bid >> 1, bn = bid & 1;
  int m0 = bm*BM;
  int lane = tid & 63, wid = tid >> 6;
  int wm = wid >> 2, wn = wid & 3;
  int lo = lane & 15, hi = lane >> 4;

  wqs[tid]     = wq[tid];
  wqs[tid+512] = wq[tid+512];

  int ar = tid >> 2, ac = (tid & 3) * 8;
  const float* asrc = x + (size_t)(m0 + ar)*DQ + ac;
  const short* bsrc = w1t + (size_t)(bn*BN + (tid>>2))*DQ + (tid&3)*8;

  float w2v[4], b1v[4];
  #pragma unroll
  for (int fn=0;fn<4;fn++){
    int n = bn*BN + wn*64 + fn*16 + lo;
    w2v[fn] = w2[n]; b1v[fn] = b1[n];
  }

  // ---- prologue: stage k0=0
  f32x4 r0 = *(const f32x4*)(asrc);
  f32x4 r1 = *(const f32x4*)(asrc + 4);
  gload_lds16(bsrc,                    &Bs[0][tid*8]);
  gload_lds16(bsrc + (size_t)128*DQ,   &Bs[0][tid*8 + 4096]);
  __syncthreads();   // wqs visible; Bs[0] drained (barrier implies vmcnt(0))
  float xqacc = 0.f;
  {
    if (bn == 0){
      f32x4 w0 = *(const f32x4*)(wqs + ac);
      f32x4 w1v = *(const f32x4*)(wqs + ac + 4);
      #pragma unroll
      for (int j=0;j<4;j++)
        xqacc += r0[j]*w0[j] + r1[j]*w1v[j];
    }
    bf16x8 s0;
    #pragma unroll
    for (int j=0;j<4;j++){ s0[j]=f2bf(r0[j]); s0[4+j]=f2bf(r1[j]); }
    *(bf16x8*)(&As[0][ar*BK + ac]) = s0;
  }
  __syncthreads();

  f32x4 acc[4][4];
  #pragma unroll
  for (int a=0;a<4;a++)
    #pragma unroll
    for (int b=0;b<4;b++) acc[a][b] = (f32x4){0.f,0.f,0.f,0.f};

  for (int t=0;t<32;t++){
    int cur = t & 1, nxt = cur ^ 1;
    int k0n = (t+1)*BK;
    if (t < 31){
      r0 = *(const f32x4*)(asrc + k0n);
      r1 = *(const f32x4*)(asrc + k0n + 4);
      gload_lds16(bsrc + k0n,                  &Bs[nxt][tid*8]);
      gload_lds16(bsrc + (size_t)128*DQ + k0n, &Bs[nxt][tid*8 + 4096]);
    }
    bf16x8 af[4], bfr[4];
    #pragma unroll
    for (int fm=0;fm<4;fm++)
      af[fm] = *(const bf16x8*)(&As[cur][(wm*64+fm*16+lo)*BK + hi*8]);
    #pragma unroll
    for (int fn=0;fn<4;fn++)
      bfr[fn] = *(const bf16x8*)(&Bs[cur][(wn*64+fn*16+lo)*BK + hi*8]);
    #pragma unroll
    for (int fm=0;fm<4;fm++)
      #pragma unroll
      for (int fn=0;fn<4;fn++)
        acc[fm][fn] = __builtin_amdgcn_mfma_f32_16x16x32_bf16(af[fm], bfr[fn], acc[fm][fn], 0,0,0);
    if (t < 31){
      if (bn == 0){
        f32x4 w0 = *(const f32x4*)(wqs + k0n + ac);
        f32x4 w1v = *(const f32x4*)(wqs + k0n + ac + 4);
        #pragma unroll
        for (int j=0;j<4;j++)
          xqacc += r0[j]*w0[j] + r1[j]*w1v[j];
      }
      bf16x8 s0;
      #pragma unroll
      for (int j=0;j<4;j++){ s0[j]=f2bf(r0[j]); s0[4+j]=f2bf(r1[j]); }
      *(bf16x8*)(&As[nxt][ar*BK + ac]) = s0;
    }
    __syncthreads();
  }

  // xq: combine the 4 threads per row
  if (bn == 0){
    float s = xqacc;
    s += __shfl_xor(s, 1);
    s += __shfl_xor(s, 2);
    if ((tid & 3) == 0) xq[m0 + ar] = s;
  }

  // epilogue: GELU + dot w2 over this wave's 64 cols -> per-row partial strip
  #pragma unroll
  for (int fm=0;fm<4;fm++){
    #pragma unroll
    for (int j=0;j<4;j++){
      float s = 0.f;
      #pragma unroll
      for (int fn=0;fn<4;fn++){
        float h = acc[fm][fn][j] + b1v[fn];
        float g = 0.5f*h*(1.0f + erff(h*0.70710678118f));
        s += g*w2v[fn];
      }
      s += __shfl_xor(s,1); s += __shfl_xor(s,2);
      s += __shfl_xor(s,4); s += __shfl_xor(s,8);
      if (lo == 0){
        int p = bn*4 + wn;
        gpart[(size_t)p*MQ + m0 + wm*64 + fm*16 + hi*4 + j] = s;
      }
    }
  }
}

// ---- fused w-phase + pooling: 1024 blocks x 64 rows.
__global__ __launch_bounds__(256) void k_wpool(
    const float* __restrict__ x, const float* __restrict__ gpart,
    const float* __restrict__ xqv, const float* __restrict__ wq,
    const float* __restrict__ b2p, const float* __restrict__ lamp,
    const void* __restrict__ maskp, const int* __restrict__ flag,
    const int* __restrict__ lens,
    float* __restrict__ part, float* __restrict__ wsumv)
{
  __shared__ float wrow[64];
  int blk = blockIdx.x, t = threadIdx.x;
  int batch = blk >> 5;            // 32 chunks of 64 rows per batch
  int sBase = (blk & 31) * 64;
  size_t R0 = (size_t)blk * 64;
  if (t < 64){
    size_t r = R0 + t;
    float gsum = b2p[0];
    #pragma unroll
    for (int p=0;p<8;p++) gsum += gpart[(size_t)p*MQ + r];
    float gate = 1.0f/(1.0f+expf(-gsum));
    float qb = wq[DQ];
    float lg = (gate*xqv[r] + qb)*0.03125f;
    float lam = lamp[0];
    float posl = fmaxf(lam,0.f) + log1pf(expf(-fabsf(lam)));
    int L = lens[batch];
    int s = sBase + t;
    float pen = fmaxf((float)L - 1.0f - (float)s, 0.0f);
    int fl = *flag;
    size_t mi_ = (size_t)batch*SQ + s;
    int mm = (fl==2) ? (((const unsigned char*)maskp)[mi_]!=0)
           : (fl==1) ? (((const float*)maskp)[mi_]!=0.0f)
                     : (((const int*)maskp)[mi_]!=0);
    float e = mm ? 0.0f : expf(lg - posl*pen);   // softmax denominator term
    wrow[t] = e*gate;                             // pooling weight
    float ts = e;
    #pragma unroll
    for (int o=1;o<64;o<<=1) ts += __shfl_xor(ts,o);
    if (t==0) wsumv[blk] = ts;
  }
  __syncthreads();

  int d0 = t*4;
  const float* xb = x + R0*DQ + d0;
  f32x4 a = {0.f,0.f,0.f,0.f};
  #pragma unroll 8
  for (int s=0;s<64;s++){
    float w = wrow[s];
    f32x4 v = *(const f32x4*)(xb + (size_t)s*DQ);
    a[0] += w*v[0]; a[1] += w*v[1]; a[2] += w*v[2]; a[3] += w*v[3];
  }
  *(f32x4*)(part + (size_t)blk*DQ + d0) = a;
}

// ---- final: out[b][d] = sum_c part[b*32+c][d] / sum_c wsum[b*32+c]
__global__ __launch_bounds__(256) void k_fin(const float* __restrict__ part,
                                             const float* __restrict__ wsumv,
                                             float* __restrict__ out){
  int i = blockIdx.x*256 + threadIdx.x;   // 32768
  int b = i >> 10, d = i & 1023;
  float den = 0.f;
  #pragma unroll
  for (int c=0;c<32;c++) den += wsumv[b*32+c];
  float s = 0.f;
  #pragma unroll
  for (int c=0;c<32;c++) s += part[((size_t)(b*32+c))*DQ + d];
  out[i] = s/den;
}

extern "C" void kernel_launch(void* const* d_in, const int* in_sizes, int n_in,
                              void* d_out, int out_size, void* d_ws, size_t ws_size,
                              hipStream_t stream)
{
  const float* x    = (const float*)d_in[0];
  const void*  mask = d_in[1];
  const float* w1   = (const float*)d_in[2];
  const float* b1   = (const float*)d_in[3];
  const float* w2   = (const float*)d_in[4];
  const float* b2   = (const float*)d_in[5];
  const float* lam  = (const float*)d_in[6];
  const float* q    = (const float*)d_in[7];
  const float* kw   = (const float*)d_in[8];
  const float* kb   = (const float*)d_in[9];
  char* ws = (char*)d_ws;
  short* w1t   = (short*)ws;                             // 1 MB
  float* wq    = (float*)(ws + (1<<20));                 // 8 KB (1025 floats)
  int*   flag  = (int*)(ws + (1<<20) + 8192);            // 4 B
  int*   lens  = (int*)(ws + (1<<20) + 8448);            // 128 B
  float* wsumv = (float*)(ws + (1<<20) + 12544);         // 4 KB (1024)
  float* xqv   = (float*)(ws + (1<<20) + 32768);         // 256 KB
  float* gpart = (float*)(ws + (2<<20));                 // 2 MB (8 x MQ)
  float* part  = (float*)(ws + (4<<20));                 // 4 MB (1024 x 1024)
  float* out   = (float*)d_out;

  k_det<<<dim3(1), 256, 0, stream>>>((const uint4*)mask, flag);
  k_prep<<<dim3(1185), 256, 0, stream>>>(w1, w1t, kw, kb, q, wq,
                                         mask, flag, lens);
  k_gate<<<dim3((MQ/BM)*(NQ/BN)), 512, 0, stream>>>(x, w1t, wq, w2, b1,
                                                    gpart, xqv);
  k_wpool<<<dim3(MQ/64), 256, 0, stream>>>(x, gpart, xqv, wq, b2, lam,
                                           mask, flag, lens, part, wsumv);
  k_fin<<<dim3((BQ*DQ)/256), 256, 0, stream>>>(part, wsumv, out);
}